// Round 20
// baseline (109.448 us; speedup 1.0000x reference)
//
#include <hip/hip_runtime.h>

typedef _Float16 h16;
typedef _Float16 h16x4 __attribute__((ext_vector_type(4)));
typedef _Float16 h16x8 __attribute__((ext_vector_type(8)));
typedef __fp16 fp16x2 __attribute__((ext_vector_type(2)));   // cvt_pkrtz native type
typedef float f32x4 __attribute__((ext_vector_type(4)));
typedef float f32x16 __attribute__((ext_vector_type(16)));

#define SEQ 2048
#define RSTRIDE 8192   // b*h*d = 4*16*128
#define QTILE 256
#define NQT (SEQ / QTILE)   // 8
#define KBLK 64
#define KPAD 136       // K LDS row stride (halves): b128 r/w conflict-free in 8-lane groups
#define VPAD 76        // V LDS row stride (halves): 6-bank row step, bijective over 16 lanes
#define DEFER_THR 8.0f

static __device__ __forceinline__ h16x8 pack8(f32x4 a, f32x4 b) {
    union { fp16x2 h2[4]; h16x8 h8; } u;
    u.h2[0] = __builtin_amdgcn_cvt_pkrtz(a[0], a[1]);
    u.h2[1] = __builtin_amdgcn_cvt_pkrtz(a[2], a[3]);
    u.h2[2] = __builtin_amdgcn_cvt_pkrtz(b[0], b[1]);
    u.h2[3] = __builtin_amdgcn_cvt_pkrtz(b[2], b[3]);
    return u.h8;
}

static __device__ __forceinline__ h16x4 pack4(float x0, float x1, float x2, float x3) {
    union { fp16x2 h2[2]; h16x4 h4; } u;
    u.h2[0] = __builtin_amdgcn_cvt_pkrtz(x0, x1);
    u.h2[1] = __builtin_amdgcn_cvt_pkrtz(x2, x3);
    return u.h4;
}

// drain ONLY LDS ops before the barrier; register-destined global loads stay in flight
static __device__ __forceinline__ void barrier_lgkm() {
    asm volatile("s_waitcnt lgkmcnt(0)" ::: "memory");
    __builtin_amdgcn_s_barrier();
}

__global__ __launch_bounds__(512, 2)
void fa_fwd_kernel(const float* __restrict__ Qg, const float* __restrict__ Kg,
                   const float* __restrict__ Vg, float* __restrict__ Out)
{
    __shared__ __attribute__((aligned(16))) h16 Kl[2][KBLK * KPAD];   // [key][d]
    __shared__ __attribute__((aligned(16))) h16 Vt[2][128 * VPAD];    // [d][key], linear

    // XCD-aware remap (256 blocks, 1/CU): XCD x owns bh in {8x..8x+7}
    const int lin = (int)blockIdx.x + 4 * (int)blockIdx.y;   // hw XCD = lin % 8
    const int bx  = (lin >> 3) & 3;               // 0..3, pairs (bx, 7-bx)
    const int bh  = 8 * (lin & 7) + (lin >> 5);   // 0..63
    const int tid  = threadIdx.x;   // 0..511 (8 waves)
    const int wave = tid >> 6;
    const int lane = tid & 63;
    const int l31  = lane & 31;     // q-col (S^T/O) / d-col (V-read) / K-row
    const int hh   = lane >> 5;     // k-slot half
    const size_t bhoff = (size_t)bh * 128;
    const float NEGINF = -__builtin_inff();
    const float SL = 0.08838834764831845f * 1.4426950408889634f;  // (1/sqrt(128))*log2(e)

    // ---- K staging geometry
    const int krow = tid >> 4;            // 0..31 (+32*it)
    const int kd0  = (tid & 15) * 8;
    const float* kbase = Kg + (size_t)krow * RSTRIDE + bhoff + kd0;
    const int kwoff = krow * KPAD + kd0;

    // ---- V staging geometry: key-group XOR-permuted so b64 LDS writes are conflict-free
    const int vkg   = ((tid >> 5) ^ ((tid & 31) >> 2)) & 15;  // key-group 0..15
    const int vkey0 = 4 * vkg;
    const int vd0   = 4 * (tid & 31);     // 0..124
    const float* vbase = Vg + (size_t)vkey0 * RSTRIDE + bhoff + vd0;

    // ---- per-lane LDS fragment bases (32x32x16 operands)
    // K A-frag: row=l31 (+32*kb), k-elems d = 16*dk + 8*hh + j  -> b128
    const int kfoff = l31 * KPAD + 8 * hh;   // + kb*32*KPAD + dk*16
    // V B-frag: col d = l31 (+32*dt2), k-slot (hh,j) -> key 16*kk + (j&3)+8*(j>>2)+4*hh
    const int vfoff = l31 * VPAD + 4 * hh;   // + dt2*32*VPAD + kk*16 (+8)

    // ones B-fragment for the P.1 row-sum MFMA
    const h16x8 vones = h16x8{(h16)1.f,(h16)1.f,(h16)1.f,(h16)1.f,
                              (h16)1.f,(h16)1.f,(h16)1.f,(h16)1.f};

    f32x4 kra[2], krb[2], vra[4];   // prefetch registers (T14)

    for (int half = 0; half < 2; ++half) {
        const int qt = half ? (NQT - 1 - bx) : bx;
        const int q0 = qt * QTILE;
        const int wbase = q0 + wave * 32;    // wave's 32 q-rows (one 32-col tile)
        const int qrow  = wbase + l31;       // THIS lane's q-row (scalar softmax state)

        // ---- Q fragments (B-operand), pre-scaled: qf[dk][j] = SL*Q[qrow][16dk+8hh+j]
        h16x8 qf[8];
        {
            const float* qp = Qg + (size_t)qrow * RSTRIDE + bhoff + 8 * hh;
#pragma unroll
            for (int dk = 0; dk < 8; ++dk) {
                f32x4 a = *(const f32x4*)(qp + dk * 16);
                f32x4 b2 = *(const f32x4*)(qp + dk * 16 + 4);
#pragma unroll
                for (int j = 0; j < 4; ++j) { a[j] *= SL; b2[j] *= SL; }
                qf[dk] = pack8(a, b2);
            }
        }

        f32x16 o[4];    // O[q][d]: col d = l31+32*dt2, rows q = (r&3)+8(r>>2)+4hh
#pragma unroll
        for (int dt2 = 0; dt2 < 4; ++dt2)
#pragma unroll
            for (int r = 0; r < 16; ++r) o[dt2][r] = 0.f;
        f32x16 lacc;    // row-sums via P.1 MFMA, same row indexing as o
#pragma unroll
        for (int r = 0; r < 16; ++r) lacc[r] = 0.f;
        float mreg = NEGINF;   // scalar per lane (one q-row per lane)

        const int nkv = 4 * (qt + 1);

        // ---- prologue
#pragma unroll
        for (int it = 0; it < 2; ++it) {
            const float* gp = kbase + (size_t)(32 * it) * RSTRIDE;
            kra[it] = *(const f32x4*)gp;
            krb[it] = *(const f32x4*)(gp + 4);
        }
#pragma unroll
        for (int kk = 0; kk < 4; ++kk)
            vra[kk] = *(const f32x4*)(vbase + (size_t)kk * RSTRIDE);
        barrier_lgkm();   // previous half's LDS reads done before overwrite
        {
            h16* kw = &Kl[0][kwoff];
#pragma unroll
            for (int it = 0; it < 2; ++it)
                *(h16x8*)(kw + it * 32 * KPAD) = pack8(kra[it], krb[it]);
#pragma unroll
            for (int e = 0; e < 4; ++e)
                *(h16x4*)&Vt[0][(vd0 + e) * VPAD + vkey0] =
                    pack4(vra[0][e], vra[1][e], vra[2][e], vra[3][e]);
        }
        if (nkv > 1) {
            const size_t toff = (size_t)KBLK * RSTRIDE;
#pragma unroll
            for (int it = 0; it < 2; ++it) {
                const float* gp = kbase + toff + (size_t)(32 * it) * RSTRIDE;
                kra[it] = *(const f32x4*)gp;
                krb[it] = *(const f32x4*)(gp + 4);
            }
#pragma unroll
            for (int kk = 0; kk < 4; ++kk)
                vra[kk] = *(const f32x4*)(vbase + toff + (size_t)kk * RSTRIDE);
        }
        barrier_lgkm();   // buf0 visible; t1 loads stay in flight

        for (int t = 0; t < nkv; ++t) {
            const int kv0 = t * KBLK;
            const int cb = t & 1;
            const bool doc = (kv0 <= wbase + 31);   // wave-uniform

            h16x8 pa[4];   // P A-fragments per 16-key block (in-lane repack)

            // ---- phase 1: QK (S^T, two 32x32 tiles) + scalar-per-lane softmax
            if (doc) {
                const h16* Kfb = &Kl[cb][kfoff];
                f32x16 sacc[2];
#pragma unroll
                for (int kb = 0; kb < 2; ++kb)
#pragma unroll
                    for (int r = 0; r < 16; ++r) sacc[kb][r] = 0.f;
#pragma unroll
                for (int kb = 0; kb < 2; ++kb) {
#pragma unroll
                    for (int dk = 0; dk < 8; ++dk) {
                        h16x8 a = *(const h16x8*)(Kfb + kb * 32 * KPAD + dk * 16);
                        sacc[kb] = __builtin_amdgcn_mfma_f32_32x32x16_f16(a, qf[dk], sacc[kb], 0, 0, 0);
                    }
                }

                // mask + per-lane max (this lane's q-row only)
                float vmax;
                if (kv0 + 63 <= wbase) {       // interior
                    float p0 = NEGINF, p1 = NEGINF, p2 = NEGINF, p3 = NEGINF;
#pragma unroll
                    for (int kb = 0; kb < 2; ++kb)
#pragma unroll
                        for (int r = 0; r < 16; r += 4) {
                            p0 = fmaxf(p0, sacc[kb][r]);
                            p1 = fmaxf(p1, sacc[kb][r + 1]);
                            p2 = fmaxf(p2, sacc[kb][r + 2]);
                            p3 = fmaxf(p3, sacc[kb][r + 3]);
                        }
                    vmax = fmaxf(fmaxf(p0, p1), fmaxf(p2, p3));
                } else {
                    vmax = NEGINF;
#pragma unroll
                    for (int kb = 0; kb < 2; ++kb)
#pragma unroll
                        for (int r = 0; r < 16; ++r) {
                            const int key = kv0 + 32 * kb + (r & 3) + 8 * (r >> 2) + 4 * hh;
                            float sv = (key <= qrow) ? sacc[kb][r] : NEGINF;
                            sacc[kb][r] = sv;
                            vmax = fmaxf(vmax, sv);
                        }
                }
                // full row max: partner lane l^32 holds the other key half of same q
                const float rmax = fmaxf(vmax, __shfl_xor(vmax, 32, 64));

                // T13 defer-max: rescale only when some row grew past threshold
                if (__any(rmax > mreg + DEFER_THR)) {
                    const float mnew  = fmaxf(mreg, rmax);
                    const float alpha = __builtin_amdgcn_exp2f(mreg - mnew);
                    mreg = mnew;
#pragma unroll
                    for (int r = 0; r < 16; ++r) {
                        const float ar = __shfl(alpha, (r & 3) + 8 * (r >> 2) + 4 * hh, 64);
                        lacc[r] *= ar;
#pragma unroll
                        for (int dt2 = 0; dt2 < 4; ++dt2) o[dt2][r] *= ar;
                    }
                }

                // P = exp2(S - m): m is SCALAR per lane
#pragma unroll
                for (int kb = 0; kb < 2; ++kb)
#pragma unroll
                    for (int r = 0; r < 16; ++r)
                        sacc[kb][r] = __builtin_amdgcn_exp2f(sacc[kb][r] - mreg);

                // P A-fragments: slot (hh,j) of k-block kk <- sacc[kk>>1][j + 8*(kk&1)]
#pragma unroll
                for (int kk = 0; kk < 4; ++kk) {
                    const int kb = kk >> 1, b0 = (kk & 1) * 8;
                    pa[kk] = pack8(
                        f32x4{sacc[kb][b0], sacc[kb][b0 + 1], sacc[kb][b0 + 2], sacc[kb][b0 + 3]},
                        f32x4{sacc[kb][b0 + 4], sacc[kb][b0 + 5], sacc[kb][b0 + 6], sacc[kb][b0 + 7]});
                }
                // row-sums: lacc rows q += sum_k P (same row layout as o)
#pragma unroll
                for (int kk = 0; kk < 4; ++kk)
                    lacc = __builtin_amdgcn_mfma_f32_32x32x16_f16(pa[kk], vones, lacc, 0, 0, 0);
            }

            // ---- phase 2: staging writes t+1 (hide under PV below)
            if (t + 1 < nkv) {
                h16* kw = &Kl[cb ^ 1][kwoff];
#pragma unroll
                for (int it = 0; it < 2; ++it)
                    *(h16x8*)(kw + it * 32 * KPAD) = pack8(kra[it], krb[it]);
#pragma unroll
                for (int e = 0; e < 4; ++e)
                    *(h16x4*)&Vt[cb ^ 1][(vd0 + e) * VPAD + vkey0] =
                        pack4(vra[0][e], vra[1][e], vra[2][e], vra[3][e]);
            }
            // ---- phase 3: issue t+2 global loads (L2 latency covered by PV)
            if (t + 2 < nkv) {
                const size_t toff = (size_t)(kv0 + 2 * KBLK) * RSTRIDE;
#pragma unroll
                for (int it = 0; it < 2; ++it) {
                    const float* gp = kbase + toff + (size_t)(32 * it) * RSTRIDE;
                    kra[it] = *(const f32x4*)gp;
                    krb[it] = *(const f32x4*)(gp + 4);
                }
#pragma unroll
                for (int kk = 0; kk < 4; ++kk)
                    vra[kk] = *(const f32x4*)(vbase + toff + (size_t)kk * RSTRIDE);
            }

            // ---- phase 4: PV: O[q][d] += P.V, V B-frags from Vt[d][key] (conflict-free)
            if (doc) {
                const h16* Vfb = &Vt[cb][vfoff];
#pragma unroll
                for (int dt2 = 0; dt2 < 4; ++dt2) {
#pragma unroll
                    for (int kk = 0; kk < 4; ++kk) {
                        union { h16x8 v8; h16x4 v4[2]; } bv;
                        bv.v4[0] = *(const h16x4*)(Vfb + dt2 * 32 * VPAD + kk * 16);
                        bv.v4[1] = *(const h16x4*)(Vfb + dt2 * 32 * VPAD + kk * 16 + 8);
                        o[dt2] = __builtin_amdgcn_mfma_f32_32x32x16_f16(pa[kk], bv.v8, o[dt2], 0, 0, 0);
                    }
                }
            }
            barrier_lgkm();   // single barrier per tile; global prefetch stays in flight
        } // kv tiles

        // ---- epilogue: divide rows by lacc (in-lane), coalesced store (d = l31+32*dt2)
#pragma unroll
        for (int r = 0; r < 16; ++r) {
            const float inv = 1.0f / lacc[r];
            const int qr    = wbase + (r & 3) + 8 * (r >> 2) + 4 * hh;
            float* op = Out + (size_t)qr * RSTRIDE + bhoff + l31;
#pragma unroll
            for (int dt2 = 0; dt2 < 4; ++dt2) op[dt2 * 32] = o[dt2][r] * inv;
        }
    } // half
}

extern "C" void kernel_launch(void* const* d_in, const int* in_sizes, int n_in,
                              void* d_out, int out_size, void* d_ws, size_t ws_size,
                              hipStream_t stream) {
    (void)in_sizes; (void)n_in; (void)out_size; (void)d_ws; (void)ws_size;
    const float* Q = (const float*)d_in[0];
    const float* K = (const float*)d_in[1];
    const float* V = (const float*)d_in[2];
    float* O = (float*)d_out;
    fa_fwd_kernel<<<dim3(NQT / 2, 64), 512, 0, stream>>>(Q, K, V, O);
}